// Round 1
// baseline (102.842 us; speedup 1.0000x reference)
//
#include <hip/hip_runtime.h>
#include <hip/hip_bf16.h>

// EmbeddingBag(mode='sum') + bias.
// inputs: feature_indices [BATCH*BAG] int32, offsets [BATCH] int32,
//         table [6144,256] fp32, bias [256] fp32
// output: [BATCH, 256] fp32
//
// One wave (64 lanes) per bag; each lane holds 4 hidden dims (float4).
// Each bag-element iteration reads one contiguous 1KB table row per wave
// (fully coalesced, 16B/lane). Table (6MB) is L2/L3-resident -> gather
// stream is cache-BW bound (~503 MB through L2).

__global__ __launch_bounds__(256) void embag_sum_kernel(
    const int* __restrict__ idx,
    const int* __restrict__ offsets,
    const float* __restrict__ table,
    const float* __restrict__ bias,
    float* __restrict__ out,
    int n_total, int batch) {
  const int wave = (int)((blockIdx.x * blockDim.x + threadIdx.x) >> 6);
  const int lane = (int)(threadIdx.x & 63);
  if (wave >= batch) return;

  const int start = offsets[wave];
  const int end   = (wave + 1 < batch) ? offsets[wave + 1] : n_total;

  const int h4 = lane * 4;  // this lane's 4 hidden dims
  float4 acc = *(const float4*)(bias + h4);

  int j = start;
  // Unroll by 2: keep two independent 16B loads in flight per lane.
  for (; j + 1 < end; j += 2) {
    const int r0 = idx[j];
    const int r1 = idx[j + 1];
    float4 v0 = *(const float4*)(table + (size_t)r0 * 256 + h4);
    float4 v1 = *(const float4*)(table + (size_t)r1 * 256 + h4);
    acc.x += v0.x; acc.y += v0.y; acc.z += v0.z; acc.w += v0.w;
    acc.x += v1.x; acc.y += v1.y; acc.z += v1.z; acc.w += v1.w;
  }
  if (j < end) {
    const int r0 = idx[j];
    float4 v0 = *(const float4*)(table + (size_t)r0 * 256 + h4);
    acc.x += v0.x; acc.y += v0.y; acc.z += v0.z; acc.w += v0.w;
  }

  *(float4*)(out + (size_t)wave * 256 + h4) = acc;
}

extern "C" void kernel_launch(void* const* d_in, const int* in_sizes, int n_in,
                              void* d_out, int out_size, void* d_ws, size_t ws_size,
                              hipStream_t stream) {
  const int*   idx     = (const int*)d_in[0];
  const int*   offsets = (const int*)d_in[1];
  const float* table   = (const float*)d_in[2];
  const float* bias    = (const float*)d_in[3];
  float*       out     = (float*)d_out;

  const int n_total = in_sizes[0];   // BATCH*BAG = 491520
  const int batch   = in_sizes[1];   // 16384

  // one wave per bag, 4 waves (256 threads) per block
  const int waves_per_block = 4;
  const int grid = (batch + waves_per_block - 1) / waves_per_block;
  embag_sum_kernel<<<grid, 256, 0, stream>>>(idx, offsets, table, bias, out,
                                             n_total, batch);
}

// Round 2
// 99.308 us; speedup vs baseline: 1.0356x; 1.0356x over previous
//
#include <hip/hip_runtime.h>
#include <hip/hip_bf16.h>

// EmbeddingBag(mode='sum') + bias.
// inputs: feature_indices [BATCH*BAG] int32, offsets [BATCH] int32,
//         table [6144,256] fp32, bias [256] fp32
// output: [BATCH, 256] fp32
//
// One wave (64 lanes) per bag; lane owns 4 hidden dims (float4) -> each
// bag-element read is one contiguous 1KB table row per wave (coalesced,
// 16B/lane). Key structure: all bag indices are fetched in ONE coalesced
// lane-parallel load, then broadcast with __shfl (ds_bpermute, no VMEM
// dependency) so table-row loads issue back-to-back. Unroll-4 keeps 4
// row loads in flight per wave; x32 waves/CU saturates the L2 request
// pipe. Table (6 MB) is L2/L3-resident -> gather is cache-BW bound.

__global__ __launch_bounds__(256) void embag_sum_kernel(
    const int* __restrict__ idx,
    const int* __restrict__ offsets,
    const float* __restrict__ table,
    const float* __restrict__ bias,
    float* __restrict__ out,
    int n_total, int batch) {
  const int bag  = (int)((blockIdx.x * blockDim.x + threadIdx.x) >> 6);
  const int lane = (int)(threadIdx.x & 63);
  if (bag >= batch) return;

  const int start = offsets[bag];
  const int end   = (bag + 1 < batch) ? offsets[bag + 1] : n_total;

  const int h4 = lane * 4;  // this lane's 4 hidden dims
  float4 acc = *(const float4*)(bias + h4);

  // Process bag indices in rounds of <=64 (one lane-parallel index load
  // per round). For this problem cnt==30, so a single round.
  for (int base = start; base < end; base += 64) {
    const int cnt = min(64, end - base);
    const int my = (lane < cnt) ? idx[base + lane] : 0;

    int k = 0;
    for (; k + 4 <= cnt; k += 4) {
      const int r0 = __shfl(my, k);
      const int r1 = __shfl(my, k + 1);
      const int r2 = __shfl(my, k + 2);
      const int r3 = __shfl(my, k + 3);
      const float4 v0 = *(const float4*)(table + (size_t)r0 * 256 + h4);
      const float4 v1 = *(const float4*)(table + (size_t)r1 * 256 + h4);
      const float4 v2 = *(const float4*)(table + (size_t)r2 * 256 + h4);
      const float4 v3 = *(const float4*)(table + (size_t)r3 * 256 + h4);
      acc.x += v0.x; acc.y += v0.y; acc.z += v0.z; acc.w += v0.w;
      acc.x += v1.x; acc.y += v1.y; acc.z += v1.z; acc.w += v1.w;
      acc.x += v2.x; acc.y += v2.y; acc.z += v2.z; acc.w += v2.w;
      acc.x += v3.x; acc.y += v3.y; acc.z += v3.z; acc.w += v3.w;
    }
    for (; k < cnt; ++k) {
      const int r = __shfl(my, k);
      const float4 v = *(const float4*)(table + (size_t)r * 256 + h4);
      acc.x += v.x; acc.y += v.y; acc.z += v.z; acc.w += v.w;
    }
  }

  *(float4*)(out + (size_t)bag * 256 + h4) = acc;
}

extern "C" void kernel_launch(void* const* d_in, const int* in_sizes, int n_in,
                              void* d_out, int out_size, void* d_ws, size_t ws_size,
                              hipStream_t stream) {
  const int*   idx     = (const int*)d_in[0];
  const int*   offsets = (const int*)d_in[1];
  const float* table   = (const float*)d_in[2];
  const float* bias    = (const float*)d_in[3];
  float*       out     = (float*)d_out;

  const int n_total = in_sizes[0];   // BATCH*BAG = 491520
  const int batch   = in_sizes[1];   // 16384

  // one wave per bag, 4 waves (256 threads) per block
  const int waves_per_block = 4;
  const int grid = (batch + waves_per_block - 1) / waves_per_block;
  embag_sum_kernel<<<grid, 256, 0, stream>>>(idx, offsets, table, bias, out,
                                             n_total, batch);
}